// Round 3
// baseline (262.540 us; speedup 1.0000x reference)
//
#include <hip/hip_runtime.h>
#include <cstdint>

// Problem constants: features (B=4, C=256, H=64, W=64) fp32,
// rois (N=2000, 5) fp32, output (N, C, 7, 7) fp32.
constexpr int CCH = 256;
constexpr int HH  = 64;
constexpr int WW  = 64;
constexpr int OHW = 49;
constexpr float RSCALE = 0.0625f;

// Bit-exact fp32 ops on the coordinate path (xs<64 validity test is the only
// discontinuity in the op).
#define FMUL __fmul_rn
#define FADD __fadd_rn
#define FSUB __fsub_rn
#define FDIV __fdiv_rn

__device__ __forceinline__ float4 f4max(float4 a, float4 b) {
  return make_float4(fmaxf(a.x, b.x), fmaxf(a.y, b.y),
                     fmaxf(a.z, b.z), fmaxf(a.w, b.w));
}

// ---------------------------------------------------------------------------
// Transpose (B, C, H*W) -> (B, H*W, C). 64ch x 64sp tile per block, float4
// global I/O (1 KB/wave-instr), LDS 64x65 (<=2-way conflicts, free).
// ---------------------------------------------------------------------------
__global__ __launch_bounds__(256) void ktranspose2(const float* __restrict__ in,
                                                   float* __restrict__ out) {
  __shared__ float tile[64][65];
  const int b  = blockIdx.z;
  const int c0 = blockIdx.y * 64;
  const int s0 = blockIdx.x * 64;
  const int t  = threadIdx.x;
  const float* inb = in  + (size_t)b * CCH * (HH * WW);
  float*      outb = out + (size_t)b * (HH * WW) * CCH;

  const int cl = t >> 4, sq = t & 15;
#pragma unroll
  for (int k = 0; k < 4; ++k) {
    const int c = cl + 16 * k;
    const float4 v = *(const float4*)(inb + (size_t)(c0 + c) * (HH * WW) + s0 + 4 * sq);
    tile[c][4 * sq + 0] = v.x;
    tile[c][4 * sq + 1] = v.y;
    tile[c][4 * sq + 2] = v.z;
    tile[c][4 * sq + 3] = v.w;
  }
  __syncthreads();
  const int cq = t & 15, rl = t >> 4;
#pragma unroll
  for (int k = 0; k < 4; ++k) {
    const int r = rl + 16 * k;
    float4 w;
    w.x = tile[4 * cq + 0][r];
    w.y = tile[4 * cq + 1][r];
    w.z = tile[4 * cq + 2][r];
    w.w = tile[4 * cq + 3][r];
    *(float4*)(outb + (size_t)(s0 + r) * CCH + c0 + 4 * cq) = w;
  }
}

// ---------------------------------------------------------------------------
// RoIAlign + 2x2 s1 maxpool, v2. One block per roi.
// thread t: cg = t&63 -> channels 4cg..4cg+3 (float4 gather from (B,H,W,C)),
//           rq = t>>6 -> row quarter (oy {0,1},{2,3},{4,5},{6}).
// Gathers are 1 KB/wave-instr; 16 loads batched per 4-sample group for MLP.
// Output staged in LDS (ox rotated by cg%7 to kill the stride-196 8-way
// conflict), then coalesced float4 writeback.
// ---------------------------------------------------------------------------
__global__ __launch_bounds__(256, 3) void roi_kernel2(const float4* __restrict__ feat,
                                                      const float* __restrict__ rois,
                                                      float* __restrict__ out) {
  __shared__ float sout[CCH * OHW];  // 50176 B -> 3 blocks/CU
  const int n  = blockIdx.x;
  const int t  = threadIdx.x;
  const int cg = t & 63;
  const int rq = t >> 6;

  const float rb = rois[n * 5 + 0];
  const float x1 = FMUL(rois[n * 5 + 1], RSCALE);
  const float y1 = FMUL(rois[n * 5 + 2], RSCALE);
  const float x2 = FMUL(rois[n * 5 + 3], RSCALE);
  const float y2 = FMUL(rois[n * 5 + 4], RSCALE);
  const int   b  = (int)rb;
  const float bh = FDIV(FSUB(y2, y1), 7.0f);
  const float bw = FDIV(FSUB(x2, x1), 7.0f);

  // Per-column sample data (wave-uniform).
  int  xo0[8], xo1[8];
  float lx[8];
  bool xv[8];
#pragma unroll
  for (int i = 0; i < 8; ++i) {
    const float xs = FADD(x1, FMUL(bw, (float)i));
    xv[i] = (xs >= 0.0f) && (xs < (float)WW);
    const float xf = floorf(xs);
    lx[i] = FSUB(xs, xf);
    int a = (int)xf;
    a = a < 0 ? 0 : (a > WW - 1 ? WW - 1 : a);
    xo0[i] = a * (CCH / 4);                                   // float4 offset
    xo1[i] = ((a + 1 > WW - 1) ? WW - 1 : a + 1) * (CCH / 4);
  }

  const float4* fb = feat + (size_t)b * (HH * WW) * (CCH / 4) + cg;

  const int jbeg = 2 * rq;
  const int jend = (rq == 3) ? 7 : jbeg + 2;
  const int oxs  = cg % 7;  // LDS scatter rotation start

  float4 hp[7];
  for (int j = jbeg; j <= jend; ++j) {
    const float ys = FADD(y1, FMUL(bh, (float)j));
    const bool  yv = (ys >= 0.0f) && (ys < (float)HH);
    const float yf = floorf(ys);
    const float ly = FSUB(ys, yf);
    int d = (int)yf;
    d = d < 0 ? 0 : (d > HH - 1 ? HH - 1 : d);
    const int d1 = (d + 1 > HH - 1) ? HH - 1 : d + 1;
    const float4* r0 = fb + (size_t)d  * (WW * (CCH / 4));
    const float4* r1 = fb + (size_t)d1 * (WW * (CCH / 4));
    const float wy1 = ly, wy0 = 1.0f - ly;

    float4 v[8];
#pragma unroll
    for (int h = 0; h < 2; ++h) {
      float4 f00[4], f01[4], f10[4], f11[4];
#pragma unroll
      for (int q = 0; q < 4; ++q) {      // 16 independent 1 KB loads in flight
        const int i = 4 * h + q;
        f00[q] = r0[xo0[i]];
        f01[q] = r0[xo1[i]];
        f10[q] = r1[xo0[i]];
        f11[q] = r1[xo1[i]];
      }
#pragma unroll
      for (int q = 0; q < 4; ++q) {
        const int i = 4 * h + q;
        const bool ok = yv && xv[i];     // wave-uniform
        const float wx1 = lx[i], wx0 = 1.0f - wx1;
        const float a00 = wy0 * wx0, a01 = wy0 * wx1;
        const float a10 = wy1 * wx0, a11 = wy1 * wx1;
        float4 r;
        r.x = a00 * f00[q].x + a01 * f01[q].x + a10 * f10[q].x + a11 * f11[q].x;
        r.y = a00 * f00[q].y + a01 * f01[q].y + a10 * f10[q].y + a11 * f11[q].y;
        r.z = a00 * f00[q].z + a01 * f01[q].z + a10 * f10[q].z + a11 * f11[q].z;
        r.w = a00 * f00[q].w + a01 * f01[q].w + a10 * f10[q].w + a11 * f11[q].w;
        v[i] = ok ? r : make_float4(0.f, 0.f, 0.f, 0.f);
      }
    }

    float4 hc[7];
#pragma unroll
    for (int i = 0; i < 7; ++i) hc[i] = f4max(v[i], v[i + 1]);

    if (j > jbeg) {
      const int oy = j - 1;
#pragma unroll
      for (int m = 0; m < 7; ++m) {
        int ox = oxs + m;
        if (ox >= 7) ox -= 7;
        const float4 r = f4max(hp[ox], hc[ox]);
        float* p = &sout[(4 * cg) * OHW + oy * 7 + ox];
        p[0 * OHW] = r.x;
        p[1 * OHW] = r.y;
        p[2 * OHW] = r.z;
        p[3 * OHW] = r.w;
      }
    }
#pragma unroll
    for (int i = 0; i < 7; ++i) hp[i] = hc[i];
  }

  __syncthreads();
  // Coalesced float4 writeback: 3136 float4 over 256 threads.
  float4* o4 = (float4*)(out + (size_t)n * (CCH * OHW));
  const float4* s4 = (const float4*)sout;
#pragma unroll
  for (int m = 0; m < 13; ++m) {
    const int idx = m * 256 + t;
    if (idx < (CCH * OHW) / 4) o4[idx] = s4[idx];
  }
}

// ---------------------------------------------------------------------------
// Fallback (workspace too small for the transposed copy): round-2 scalar path.
// ---------------------------------------------------------------------------
__global__ __launch_bounds__(256) void roi_kernel_fb(const float* __restrict__ feat,
                                                     const float* __restrict__ rois,
                                                     float* __restrict__ out) {
  __shared__ float sout[CCH * OHW];
  const int n = blockIdx.x;
  const int c = threadIdx.x;

  const float rb = rois[n * 5 + 0];
  const float x1 = FMUL(rois[n * 5 + 1], RSCALE);
  const float y1 = FMUL(rois[n * 5 + 2], RSCALE);
  const float x2 = FMUL(rois[n * 5 + 3], RSCALE);
  const float y2 = FMUL(rois[n * 5 + 4], RSCALE);
  const int b = (int)rb;
  const float bh = FDIV(FSUB(y2, y1), 7.0f);
  const float bw = FDIV(FSUB(x2, x1), 7.0f);

  int ix0[8], ix1[8], iy0[8], iy1[8];
  float lx[8], ly[8];
  bool xv[8], yv[8];
#pragma unroll
  for (int i = 0; i < 8; ++i) {
    const float xs = FADD(x1, FMUL(bw, (float)i));
    const float ys = FADD(y1, FMUL(bh, (float)i));
    xv[i] = (xs >= 0.0f) && (xs < (float)WW);
    yv[i] = (ys >= 0.0f) && (ys < (float)HH);
    const float xf = floorf(xs);
    const float yf = floorf(ys);
    lx[i] = FSUB(xs, xf);
    ly[i] = FSUB(ys, yf);
    int a = (int)xf;
    a = a < 0 ? 0 : (a > WW - 1 ? WW - 1 : a);
    ix0[i] = a;
    ix1[i] = (a + 1 > WW - 1) ? WW - 1 : a + 1;
    int d = (int)yf;
    d = d < 0 ? 0 : (d > HH - 1 ? HH - 1 : d);
    iy0[i] = d;
    iy1[i] = (d + 1 > HH - 1) ? HH - 1 : d + 1;
  }

  const float* fbp = feat + ((size_t)b * CCH + c) * (size_t)(HH * WW);
  float hp[7];
#pragma unroll
  for (int j = 0; j < 8; ++j) {
    float v[8];
    const float wy1 = ly[j], wy0 = 1.0f - ly[j];
#pragma unroll
    for (int i = 0; i < 8; ++i) {
      if (yv[j] && xv[i]) {
        const float f00 = fbp[iy0[j] * WW + ix0[i]];
        const float f01 = fbp[iy0[j] * WW + ix1[i]];
        const float f10 = fbp[iy1[j] * WW + ix0[i]];
        const float f11 = fbp[iy1[j] * WW + ix1[i]];
        const float wx1 = lx[i], wx0 = 1.0f - wx1;
        v[i] = wy0 * (wx0 * f00 + wx1 * f01) + wy1 * (wx0 * f10 + wx1 * f11);
      } else {
        v[i] = 0.0f;
      }
    }
    float hc[7];
#pragma unroll
    for (int i = 0; i < 7; ++i) hc[i] = fmaxf(v[i], v[i + 1]);
    if (j > 0) {
#pragma unroll
      for (int i = 0; i < 7; ++i)
        sout[c * OHW + (j - 1) * 7 + i] = fmaxf(hp[i], hc[i]);
    }
#pragma unroll
    for (int i = 0; i < 7; ++i) hp[i] = hc[i];
  }
  __syncthreads();
  const float4* s4 = (const float4*)sout;
  float4* o4 = (float4*)(out + (size_t)n * (CCH * OHW));
  for (int t = c; t < (CCH * OHW) / 4; t += 256) o4[t] = s4[t];
}

extern "C" void kernel_launch(void* const* d_in, const int* in_sizes, int n_in,
                              void* d_out, int out_size, void* d_ws, size_t ws_size,
                              hipStream_t stream) {
  (void)n_in; (void)out_size;
  const float* feat = (const float*)d_in[0];
  const float* rois = (const float*)d_in[1];
  float* out = (float*)d_out;
  const int N = in_sizes[1] / 5;
  const int B = in_sizes[0] / (CCH * HH * WW);
  const size_t tneed = (size_t)in_sizes[0] * sizeof(float);

  if (ws_size >= tneed) {
    ktranspose2<<<dim3((HH * WW) / 64, CCH / 64, B), dim3(256), 0, stream>>>(
        feat, (float*)d_ws);
    roi_kernel2<<<dim3(N), dim3(256), 0, stream>>>(
        (const float4*)d_ws, rois, out);
  } else {
    roi_kernel_fb<<<dim3(N), dim3(256), 0, stream>>>(feat, rois, out);
  }
}

// Round 4
// 178.415 us; speedup vs baseline: 1.4715x; 1.4715x over previous
//
#include <hip/hip_runtime.h>
#include <cstdint>

// Problem constants: features (B=4, C=256, H=64, W=64) fp32,
// rois (N=2000, 5) fp32, output (N, C, 7, 7) fp32.
constexpr int CCH = 256;
constexpr int HH  = 64;
constexpr int WW  = 64;
constexpr int OHW = 49;
constexpr float RSCALE = 0.0625f;

// Bit-exact fp32 ops on the coordinate path (xs<64 validity test is the only
// discontinuity in the op).
#define FMUL __fmul_rn
#define FADD __fadd_rn
#define FSUB __fsub_rn
#define FDIV __fdiv_rn

__device__ __forceinline__ float4 f4max(float4 a, float4 b) {
  return make_float4(fmaxf(a.x, b.x), fmaxf(a.y, b.y),
                     fmaxf(a.z, b.z), fmaxf(a.w, b.w));
}

// ---------------------------------------------------------------------------
// Transpose (B, C, H*W) -> (B, H*W, C). 64ch x 64sp tile per block, float4
// global I/O, LDS 64x65 (<=2-way conflicts, free).
// ---------------------------------------------------------------------------
__global__ __launch_bounds__(256) void ktranspose2(const float* __restrict__ in,
                                                   float* __restrict__ out) {
  __shared__ float tile[64][65];
  const int b  = blockIdx.z;
  const int c0 = blockIdx.y * 64;
  const int s0 = blockIdx.x * 64;
  const int t  = threadIdx.x;
  const float* inb = in  + (size_t)b * CCH * (HH * WW);
  float*      outb = out + (size_t)b * (HH * WW) * CCH;

  const int cl = t >> 4, sq = t & 15;
#pragma unroll
  for (int k = 0; k < 4; ++k) {
    const int c = cl + 16 * k;
    const float4 v = *(const float4*)(inb + (size_t)(c0 + c) * (HH * WW) + s0 + 4 * sq);
    tile[c][4 * sq + 0] = v.x;
    tile[c][4 * sq + 1] = v.y;
    tile[c][4 * sq + 2] = v.z;
    tile[c][4 * sq + 3] = v.w;
  }
  __syncthreads();
  const int cq = t & 15, rl = t >> 4;
#pragma unroll
  for (int k = 0; k < 4; ++k) {
    const int r = rl + 16 * k;
    float4 w;
    w.x = tile[4 * cq + 0][r];
    w.y = tile[4 * cq + 1][r];
    w.z = tile[4 * cq + 2][r];
    w.w = tile[4 * cq + 3][r];
    *(float4*)(outb + (size_t)(s0 + r) * CCH + c0 + 4 * cq) = w;
  }
}

// ---------------------------------------------------------------------------
// RoIAlign + 2x2 s1 maxpool, v3. One block per roi.
// thread t: cg = t&63 -> channel granule (4 contiguous channels, float4
// gather from the (B,H,W,C) copy); rq = t>>6 -> row quarter.
// ALL local arrays statically indexed (v2's runtime hp[ox] demoted hp/hc to
// scratch: +450 MB HBM traffic — the round-3 regression).
// LDS: channel-minor [49][64 granules], XOR-swizzled (gp = cg ^ ((s>>2)&7)):
// store = single conflict-free ds_write_b128; writeback reads <=3-way.
// ---------------------------------------------------------------------------
__global__ __launch_bounds__(256, 3) void roi_kernel3(const float4* __restrict__ feat,
                                                      const float* __restrict__ rois,
                                                      float* __restrict__ out) {
  __shared__ float sout[CCH * OHW];            // [49 rows][64 granules] swizzled
  float4* sout4 = (float4*)sout;
  const int n  = blockIdx.x;
  const int t  = threadIdx.x;
  const int cg = t & 63;
  const int rq = t >> 6;

  const float rb = rois[n * 5 + 0];
  const float x1 = FMUL(rois[n * 5 + 1], RSCALE);
  const float y1 = FMUL(rois[n * 5 + 2], RSCALE);
  const float x2 = FMUL(rois[n * 5 + 3], RSCALE);
  const float y2 = FMUL(rois[n * 5 + 4], RSCALE);
  const int   b  = (int)rb;
  const float bh = FDIV(FSUB(y2, y1), 7.0f);
  const float bw = FDIV(FSUB(x2, x1), 7.0f);

  // Per-column sample data (wave-uniform, statically indexed).
  int   xo0[8], xo1[8];
  float lx[8];
  bool  xv[8];
#pragma unroll
  for (int i = 0; i < 8; ++i) {
    const float xs = FADD(x1, FMUL(bw, (float)i));
    xv[i] = (xs >= 0.0f) && (xs < (float)WW);
    const float xf = floorf(xs);
    lx[i] = FSUB(xs, xf);
    int a = (int)xf;
    a = a < 0 ? 0 : (a > WW - 1 ? WW - 1 : a);
    xo0[i] = a * (CCH / 4);                                    // float4 units
    xo1[i] = ((a + 1 > WW - 1) ? WW - 1 : a + 1) * (CCH / 4);
  }

  const float4* fb = feat + (size_t)b * (HH * WW) * (CCH / 4) + cg;

  const int jbeg = 2 * rq;
  const int jend = (rq == 3) ? 7 : jbeg + 2;

  float4 hp[7];
  for (int j = jbeg; j <= jend; ++j) {
    const float ys = FADD(y1, FMUL(bh, (float)j));
    const bool  yv = (ys >= 0.0f) && (ys < (float)HH);
    const float yf = floorf(ys);
    const float ly = FSUB(ys, yf);
    int d = (int)yf;
    d = d < 0 ? 0 : (d > HH - 1 ? HH - 1 : d);
    const int d1 = (d + 1 > HH - 1) ? HH - 1 : d + 1;
    const float4* r0 = fb + (size_t)d  * (WW * (CCH / 4));
    const float4* r1 = fb + (size_t)d1 * (WW * (CCH / 4));
    const float wy1 = ly, wy0 = 1.0f - ly;

    float4 hc[7], vprev;
    // ---- samples 0..3: 16 independent 1 KB wave-loads in flight ----
    {
      float4 f00[4], f01[4], f10[4], f11[4];
#pragma unroll
      for (int q = 0; q < 4; ++q) {
        f00[q] = r0[xo0[q]];
        f01[q] = r0[xo1[q]];
        f10[q] = r1[xo0[q]];
        f11[q] = r1[xo1[q]];
      }
      float4 v[4];
#pragma unroll
      for (int q = 0; q < 4; ++q) {
        const bool ok = yv && xv[q];               // wave-uniform
        const float wx1 = lx[q], wx0 = 1.0f - wx1;
        const float a00 = wy0 * wx0, a01 = wy0 * wx1;
        const float a10 = wy1 * wx0, a11 = wy1 * wx1;
        float4 r;
        r.x = a00 * f00[q].x + a01 * f01[q].x + a10 * f10[q].x + a11 * f11[q].x;
        r.y = a00 * f00[q].y + a01 * f01[q].y + a10 * f10[q].y + a11 * f11[q].y;
        r.z = a00 * f00[q].z + a01 * f01[q].z + a10 * f10[q].z + a11 * f11[q].z;
        r.w = a00 * f00[q].w + a01 * f01[q].w + a10 * f10[q].w + a11 * f11[q].w;
        v[q] = ok ? r : make_float4(0.f, 0.f, 0.f, 0.f);
      }
      hc[0] = f4max(v[0], v[1]);
      hc[1] = f4max(v[1], v[2]);
      hc[2] = f4max(v[2], v[3]);
      vprev = v[3];
    }
    // ---- samples 4..7 ----
    {
      float4 f00[4], f01[4], f10[4], f11[4];
#pragma unroll
      for (int q = 0; q < 4; ++q) {
        f00[q] = r0[xo0[4 + q]];
        f01[q] = r0[xo1[4 + q]];
        f10[q] = r1[xo0[4 + q]];
        f11[q] = r1[xo1[4 + q]];
      }
      float4 v[4];
#pragma unroll
      for (int q = 0; q < 4; ++q) {
        const bool ok = yv && xv[4 + q];
        const float wx1 = lx[4 + q], wx0 = 1.0f - wx1;
        const float a00 = wy0 * wx0, a01 = wy0 * wx1;
        const float a10 = wy1 * wx0, a11 = wy1 * wx1;
        float4 r;
        r.x = a00 * f00[q].x + a01 * f01[q].x + a10 * f10[q].x + a11 * f11[q].x;
        r.y = a00 * f00[q].y + a01 * f01[q].y + a10 * f10[q].y + a11 * f11[q].y;
        r.z = a00 * f00[q].z + a01 * f01[q].z + a10 * f10[q].z + a11 * f11[q].z;
        r.w = a00 * f00[q].w + a01 * f01[q].w + a10 * f10[q].w + a11 * f11[q].w;
        v[q] = ok ? r : make_float4(0.f, 0.f, 0.f, 0.f);
      }
      hc[3] = f4max(vprev, v[0]);
      hc[4] = f4max(v[0], v[1]);
      hc[5] = f4max(v[1], v[2]);
      hc[6] = f4max(v[2], v[3]);
    }

    if (j > jbeg) {
      const int oy = j - 1;
#pragma unroll
      for (int m = 0; m < 7; ++m) {              // static m -> no scratch
        const int s  = oy * 7 + m;
        const int gp = cg ^ ((s >> 2) & 7);      // XOR swizzle
        sout4[s * (CCH / 4) + gp] = f4max(hp[m], hc[m]);
      }
    }
#pragma unroll
    for (int m = 0; m < 7; ++m) hp[m] = hc[m];
  }

  __syncthreads();
  // Coalesced float4 writeback; LDS reads de-swizzled (<=3-way conflicts).
  float4* o4 = (float4*)(out + (size_t)n * (CCH * OHW));
#pragma unroll
  for (int m = 0; m < 13; ++m) {
    const int idx = m * 256 + t;
    if (idx < (CCH * OHW) / 4) {
      const int f0 = idx * 4;
      float4 w;
      float* wp = (float*)&w;
#pragma unroll
      for (int k = 0; k < 4; ++k) {
        const int e = f0 + k;
        const int c = e / 49;                    // const divisor -> magic mul
        const int s = e - c * 49;
        wp[k] = sout[s * CCH + 4 * ((c >> 2) ^ ((s >> 2) & 7)) + (c & 3)];
      }
      o4[idx] = w;
    }
  }
}

// ---------------------------------------------------------------------------
// Fallback (workspace too small): round-2 scalar path, known-correct.
// ---------------------------------------------------------------------------
__global__ __launch_bounds__(256) void roi_kernel_fb(const float* __restrict__ feat,
                                                     const float* __restrict__ rois,
                                                     float* __restrict__ out) {
  __shared__ float sout[CCH * OHW];
  const int n = blockIdx.x;
  const int c = threadIdx.x;

  const float rb = rois[n * 5 + 0];
  const float x1 = FMUL(rois[n * 5 + 1], RSCALE);
  const float y1 = FMUL(rois[n * 5 + 2], RSCALE);
  const float x2 = FMUL(rois[n * 5 + 3], RSCALE);
  const float y2 = FMUL(rois[n * 5 + 4], RSCALE);
  const int b = (int)rb;
  const float bh = FDIV(FSUB(y2, y1), 7.0f);
  const float bw = FDIV(FSUB(x2, x1), 7.0f);

  int ix0[8], ix1[8], iy0[8], iy1[8];
  float lx[8], ly[8];
  bool xv[8], yv[8];
#pragma unroll
  for (int i = 0; i < 8; ++i) {
    const float xs = FADD(x1, FMUL(bw, (float)i));
    const float ys = FADD(y1, FMUL(bh, (float)i));
    xv[i] = (xs >= 0.0f) && (xs < (float)WW);
    yv[i] = (ys >= 0.0f) && (ys < (float)HH);
    const float xf = floorf(xs);
    const float yf = floorf(ys);
    lx[i] = FSUB(xs, xf);
    ly[i] = FSUB(ys, yf);
    int a = (int)xf;
    a = a < 0 ? 0 : (a > WW - 1 ? WW - 1 : a);
    ix0[i] = a;
    ix1[i] = (a + 1 > WW - 1) ? WW - 1 : a + 1;
    int d = (int)yf;
    d = d < 0 ? 0 : (d > HH - 1 ? HH - 1 : d);
    iy0[i] = d;
    iy1[i] = (d + 1 > HH - 1) ? HH - 1 : d + 1;
  }

  const float* fbp = feat + ((size_t)b * CCH + c) * (size_t)(HH * WW);
  float hp[7];
#pragma unroll
  for (int j = 0; j < 8; ++j) {
    float v[8];
    const float wy1 = ly[j], wy0 = 1.0f - ly[j];
#pragma unroll
    for (int i = 0; i < 8; ++i) {
      if (yv[j] && xv[i]) {
        const float f00 = fbp[iy0[j] * WW + ix0[i]];
        const float f01 = fbp[iy0[j] * WW + ix1[i]];
        const float f10 = fbp[iy1[j] * WW + ix0[i]];
        const float f11 = fbp[iy1[j] * WW + ix1[i]];
        const float wx1 = lx[i], wx0 = 1.0f - wx1;
        v[i] = wy0 * (wx0 * f00 + wx1 * f01) + wy1 * (wx0 * f10 + wx1 * f11);
      } else {
        v[i] = 0.0f;
      }
    }
    float hc[7];
#pragma unroll
    for (int i = 0; i < 7; ++i) hc[i] = fmaxf(v[i], v[i + 1]);
    if (j > 0) {
#pragma unroll
      for (int i = 0; i < 7; ++i)
        sout[c * OHW + (j - 1) * 7 + i] = fmaxf(hp[i], hc[i]);
    }
#pragma unroll
    for (int i = 0; i < 7; ++i) hp[i] = hc[i];
  }
  __syncthreads();
  const float4* s4 = (const float4*)sout;
  float4* o4 = (float4*)(out + (size_t)n * (CCH * OHW));
  for (int q = c; q < (CCH * OHW) / 4; q += 256) o4[q] = s4[q];
}

extern "C" void kernel_launch(void* const* d_in, const int* in_sizes, int n_in,
                              void* d_out, int out_size, void* d_ws, size_t ws_size,
                              hipStream_t stream) {
  (void)n_in; (void)out_size;
  const float* feat = (const float*)d_in[0];
  const float* rois = (const float*)d_in[1];
  float* out = (float*)d_out;
  const int N = in_sizes[1] / 5;
  const int B = in_sizes[0] / (CCH * HH * WW);
  const size_t tneed = (size_t)in_sizes[0] * sizeof(float);

  if (ws_size >= tneed) {
    ktranspose2<<<dim3((HH * WW) / 64, CCH / 64, B), dim3(256), 0, stream>>>(
        feat, (float*)d_ws);
    roi_kernel3<<<dim3(N), dim3(256), 0, stream>>>(
        (const float4*)d_ws, rois, out);
  } else {
    roi_kernel_fb<<<dim3(N), dim3(256), 0, stream>>>(feat, rois, out);
  }
}